// Round 5
// baseline (7003.566 us; speedup 1.0000x reference)
//
#include <hip/hip_runtime.h>
#include <hip/hip_cooperative_groups.h>

namespace cg = cooperative_groups;

// Problem constants
constexpr int Bc = 32, Sc = 512, Dc = 768, Mc = 32, Tc = 30;
constexpr int Hc = 12, DFFc = 3072, Lc = 4, Ec = 100000, HDc = 64;
constexpr int TOK = Bc * Mc; // 1024 token rows
constexpr int KC2 = 128;     // padded K for classifier GEMMs (multiple of BK=64)

typedef float floatx4 __attribute__((ext_vector_type(4)));
typedef __bf16 bfrag8 __attribute__((ext_vector_type(8)));
typedef unsigned short usx8 __attribute__((ext_vector_type(8)));
typedef unsigned short usx4 __attribute__((ext_vector_type(4)));

__device__ __forceinline__ unsigned short f32_to_bf16(float f) {
    unsigned int u = __float_as_uint(f);
    unsigned int r = (u + 0x7FFFu + ((u >> 16) & 1u)) >> 16; // RNE
    return (unsigned short)r;
}

// async global->LDS, 16B per lane; lds ptr must be wave-uniform, gsrc is per-lane
__device__ __forceinline__ void gload_lds16(const void* gsrc, void* lds) {
    __builtin_amdgcn_global_load_lds((const unsigned int*)gsrc, (unsigned int*)lds, 16, 0, 0);
}

// ---------------------------------------------------------------- fused front kernel
// block ranges: [0,1536) weight cvt segs; [1536,2048) cls_w2 cvt; [2048,3072) mention pool
struct CvtSegs {
    const float* src[7];
    unsigned short* dst[7];
    unsigned int end[7];   // cumulative counts in float4-chunks
    unsigned int total;
};

constexpr int FB_CVT1 = 1536, FB_CVT2 = 512, FB_POOL = TOK;

__global__ __launch_bounds__(256)
void front_kernel(CvtSegs a, const float* __restrict__ cw2, unsigned short* __restrict__ bw_c2,
                  const float* __restrict__ lhs, const float* __restrict__ attn_w,
                  const int* __restrict__ pos, const int* __restrict__ emask,
                  float* __restrict__ x0, unsigned short* __restrict__ x0b) {
    const int bid = blockIdx.x;
    const int tid = threadIdx.x;

    if (bid < FB_CVT1) {
        const unsigned int stride = FB_CVT1 * 256;
        for (unsigned int i = bid * 256 + tid; i < a.total; i += stride) {
            int s = 0;
            while (i >= a.end[s]) ++s;
            const unsigned int off = i - (s ? a.end[s - 1] : 0u);
            usx4 o = (usx4)0;
            if (a.src[s]) {
                floatx4 v = *(const floatx4*)(a.src[s] + 4 * (size_t)off);
                #pragma unroll
                for (int j = 0; j < 4; ++j) o[j] = f32_to_bf16(v[j]);
            }
            *(usx4*)(a.dst[s] + 4 * (size_t)off) = o;
        }
        return;
    }
    if (bid < FB_CVT1 + FB_CVT2) {
        const int total = Ec * (KC2 / 8);
        const int stride = FB_CVT2 * 256;
        for (int c = (bid - FB_CVT1) * 256 + tid; c < total; c += stride) {
            const int row = c >> 4, j = c & 15;
            const int col0 = j * 8;
            const float* sp = cw2 + (size_t)row * 100 + col0;
            usx8 o = (usx8)0;
            if (col0 + 8 <= 100) {
                floatx4 v0 = *(const floatx4*)(sp);
                floatx4 v1 = *(const floatx4*)(sp + 4);
                #pragma unroll
                for (int jj = 0; jj < 4; ++jj) { o[jj] = f32_to_bf16(v0[jj]); o[4 + jj] = f32_to_bf16(v1[jj]); }
            } else if (col0 < 100) {
                #pragma unroll
                for (int jj = 0; jj < 8; ++jj)
                    if (col0 + jj < 100) o[jj] = f32_to_bf16(sp[jj]);
            }
            *(usx8*)(bw_c2 + (size_t)row * KC2 + col0) = o;
        }
        return;
    }

    // ---- mention pool ----
    const int bm = bid - (FB_CVT1 + FB_CVT2);   // b*32+m
    const int b = bm >> 5;
    __shared__ float s_logit[32];
    __shared__ float s_w[32];
    __shared__ int s_valid[32];

    if (tid == 0) {
        int em = emask[bm];
        int ok = 1;
        for (int t = 0; t < Tc; ++t) {
            if (pos[bm * Tc + t] == -1) ok = 0;
            s_valid[t] = (ok && em) ? 1 : 0;
        }
    }
    __syncthreads();

    const int wid = tid >> 6, lane = tid & 63;
    for (int t = wid; t < Tc; t += 4) {
        float p = 0.f;
        const float* row = lhs + ((size_t)b * Sc + t) * Dc;
        for (int d = lane; d < Dc; d += 64) p += row[d] * attn_w[d];
        #pragma unroll
        for (int off = 32; off > 0; off >>= 1) p += __shfl_down(p, off);
        if (lane == 0) s_logit[t] = s_valid[t] ? p : 0.0f;  // attn_b cancels in softmax
    }
    __syncthreads();
    if (tid == 0) {
        float mx = -1e30f;
        for (int t = 0; t < Tc; ++t) mx = fmaxf(mx, s_logit[t]);
        float sum = 0.f;
        for (int t = 0; t < Tc; ++t) { float e = expf(s_logit[t] - mx); s_w[t] = e; sum += e; }
        float inv = 1.0f / sum;
        for (int t = 0; t < Tc; ++t) s_w[t] = s_valid[t] ? s_w[t] * inv : 0.0f;
    }
    __syncthreads();
    for (int d = tid; d < Dc; d += 256) {
        float acc = 0.f;
        for (int t = 0; t < Tc; ++t) acc += s_w[t] * lhs[((size_t)b * Sc + t) * Dc + d];
        x0[(size_t)bm * Dc + d] = acc;
        x0b[(size_t)bm * Dc + d] = f32_to_bf16(acc);
    }
}

// ---------------------------------------------------------------- GEMM tile device fn
// C = A @ B^T (+bias)(opt relu). A bf16 [M,lda], B bf16 [N,ldb], C f32/bf16 [M,ldc].
// REQUIRES M%BM==0, K%64==0, 16B-aligned rows. Stores guarded by col<N; B OOB rows
// must land in readable memory. global_load_lds w16, linear LDS dest + pre-swizzled
// global source (cb ^ ((row&7)<<4)); same XOR on ds_read (T2, rule #21).
// Double-buffered: stage(t+1) issued before compute(t), one __syncthreads per step.
// Split-K: A,B advance z*K cols; C advances z*M*ldc. lA/lB: 2*BM*64 / 2*BN*64 shorts.
template <int BM, int BN, int WM, int WN, int OUTBF>
__device__ __forceinline__ void gemm_tile(
    const unsigned short* __restrict__ A, int lda,
    const unsigned short* __restrict__ B, int ldb,
    const float* __restrict__ bias, void* __restrict__ Cv,
    int ldc, int M, int N, int K, int relu,
    int bx, int by, int z,
    unsigned short* lA, unsigned short* lB) {
    constexpr int BK = 64;
    A += (size_t)z * K;
    B += (size_t)z * K;

    const int tid = threadIdx.x;
    const int bm0 = by * BM;
    const int bn0 = bx * BN;

    const int wid = tid >> 6;
    const int lane = tid & 63;
    const int quad = lane >> 4;
    const int l16 = lane & 15;
    const int wr = (wid >> 1) * (WM * 16);
    const int wc = (wid & 1) * (WN * 16);

    floatx4 acc[WM][WN] = {};

    auto stageA = [&](int buf, int k0) {
        #pragma unroll
        for (int it = 0; it < BM / 32; ++it) {
            const int chunk = wid * (BM / 32) + it;       // wave-uniform
            const int boff = chunk * 1024 + lane * 16;
            const int row = boff >> 7;
            const int cb = (boff & 127) ^ ((row & 7) << 4);
            gload_lds16((const char*)(A + (size_t)(bm0 + row) * lda + k0) + cb,
                        &lA[buf * (BM * BK) + chunk * 512]);
        }
    };
    auto stageB = [&](int buf, int k0) {
        #pragma unroll
        for (int it = 0; it < BN / 32; ++it) {
            const int chunk = wid * (BN / 32) + it;
            const int boff = chunk * 1024 + lane * 16;
            const int row = boff >> 7;
            const int cb = (boff & 127) ^ ((row & 7) << 4);
            gload_lds16((const char*)(B + (size_t)(bn0 + row) * ldb + k0) + cb,
                        &lB[buf * (BN * BK) + chunk * 512]);
        }
    };

    stageA(0, 0);
    stageB(0, 0);
    __syncthreads();          // drain prologue (vmcnt) before first reads

    int c = 0;
    for (int k0 = 0; k0 < K; k0 += BK, c ^= 1) {
        const int kn = k0 + BK;
        const bool more = (kn < K);
        if (more) { stageA(c ^ 1, kn); stageB(c ^ 1, kn); }  // in flight across compute
        const unsigned short* bA = lA + c * (BM * BK);
        const unsigned short* bB = lB + c * (BN * BK);
        #pragma unroll
        for (int kk = 0; kk < BK; kk += 32) {
            bfrag8 af[WM], bfr[WN];
            #pragma unroll
            for (int i = 0; i < WM; ++i) {
                const int rowA = wr + i * 16 + l16;
                af[i] = *(const bfrag8*)((const char*)bA + rowA * 128 +
                                         ((kk * 2 + quad * 16) ^ ((rowA & 7) << 4)));
            }
            #pragma unroll
            for (int j = 0; j < WN; ++j) {
                const int rowB = wc + j * 16 + l16;
                bfr[j] = *(const bfrag8*)((const char*)bB + rowB * 128 +
                                          ((kk * 2 + quad * 16) ^ ((rowB & 7) << 4)));
            }
            #pragma unroll
            for (int i = 0; i < WM; ++i)
                #pragma unroll
                for (int j = 0; j < WN; ++j)
                    acc[i][j] = __builtin_amdgcn_mfma_f32_16x16x32_bf16(af[i], bfr[j], acc[i][j], 0, 0, 0);
        }
        if (more) __syncthreads();   // drains next-tile vmcnt + this tile's lgkm
    }

    #pragma unroll
    for (int i = 0; i < WM; ++i) {
        #pragma unroll
        for (int j = 0; j < WN; ++j) {
            const int col = bn0 + wc + j * 16 + l16;
            if (col < N) {
                const int row0 = bm0 + wr + i * 16 + quad * 4;
                const float bv = bias ? bias[col] : 0.0f;
                #pragma unroll
                for (int r = 0; r < 4; ++r) {
                    float v = acc[i][j][r] + bv;
                    if (relu) v = fmaxf(v, 0.0f);
                    const size_t idx = (size_t)z * M * ldc + (size_t)(row0 + r) * ldc + col;
                    if (OUTBF) ((unsigned short*)Cv)[idx] = f32_to_bf16(v);
                    else       ((float*)Cv)[idx] = v;
                }
            }
        }
    }
}

// ---------------------------------------------------------------- attention stage (per (b,h))
__device__ __forceinline__ void attn_stage(const float* __restrict__ qkv,
                                           unsigned short* __restrict__ outb,
                                           int bh, char* smem) {
    float (*sQ)[65] = (float(*)[65])(smem);
    float (*sK)[65] = (float(*)[65])(smem + 32 * 65 * 4);
    float (*sV)[65] = (float(*)[65])(smem + 2 * 32 * 65 * 4);
    float (*sS)[33] = (float(*)[33])(smem + 3 * 32 * 65 * 4);
    const int b = bh / Hc, h = bh % Hc;
    const int tid = threadIdx.x;

    const int m = tid >> 3;
    const int c0 = (tid & 7) * 8;
    {
        const size_t rbase = ((size_t)(b * 32 + m)) * (3 * Dc);
        #pragma unroll
        for (int j = 0; j < 8; ++j) {
            sQ[m][c0 + j] = qkv[rbase + h * HDc + c0 + j];
            sK[m][c0 + j] = qkv[rbase + Dc + h * HDc + c0 + j];
            sV[m][c0 + j] = qkv[rbase + 2 * Dc + h * HDc + c0 + j];
        }
    }
    __syncthreads();

    #pragma unroll
    for (int u = 0; u < 4; ++u) {
        const int e = tid * 4 + u;
        const int q = e >> 5, k = e & 31;
        float s = 0.f;
        #pragma unroll
        for (int d = 0; d < HDc; ++d) s += sQ[q][d] * sK[k][d];
        sS[q][k] = s * 0.125f;
    }
    __syncthreads();
    if (tid < 32) {
        float mx = -1e30f;
        for (int k = 0; k < 32; ++k) mx = fmaxf(mx, sS[tid][k]);
        float sum = 0.f;
        for (int k = 0; k < 32; ++k) { float e = expf(sS[tid][k] - mx); sS[tid][k] = e; sum += e; }
        const float inv = 1.0f / sum;
        for (int k = 0; k < 32; ++k) sS[tid][k] *= inv;
    }
    __syncthreads();
    float o[8] = {};
    for (int k = 0; k < 32; ++k) {
        const float p = sS[m][k];
        #pragma unroll
        for (int j = 0; j < 8; ++j) o[j] += p * sV[k][c0 + j];
    }
    usx8 o8;
    #pragma unroll
    for (int j = 0; j < 8; ++j) o8[j] = f32_to_bf16(o[j]);
    *(usx8*)(&outb[((size_t)(b * 32 + m)) * Dc + h * HDc + c0]) = o8;
    __syncthreads();   // protect smem reuse by next stage call in same block (belt+braces)
}

// ---------------------------------------------------------------- addLN stage (per row)
__device__ __forceinline__ void addln_stage(const float* __restrict__ xa,
                                            const float* __restrict__ xs, int nslab,
                                            const float* __restrict__ badd,
                                            const float* __restrict__ g,
                                            const float* __restrict__ be,
                                            float* __restrict__ outf,
                                            unsigned short* __restrict__ outb,
                                            int row, float* red) {
    const int tid = threadIdx.x;
    float v[3];
    float s = 0.f, sq = 0.f;
    #pragma unroll
    for (int i = 0; i < 3; ++i) {
        const int d = tid + i * 256;
        float x = xa[(size_t)row * Dc + d] + badd[d];
        for (int sl = 0; sl < nslab; ++sl)
            x += xs[((size_t)sl * TOK + row) * Dc + d];
        v[i] = x; s += x; sq += x * x;
    }
    #pragma unroll
    for (int off = 32; off > 0; off >>= 1) {
        s += __shfl_down(s, off);
        sq += __shfl_down(sq, off);
    }
    if ((tid & 63) == 0) { red[tid >> 6] = s; red[4 + (tid >> 6)] = sq; }
    __syncthreads();
    const float ts = red[0] + red[1] + red[2] + red[3];
    const float tq = red[4] + red[5] + red[6] + red[7];
    const float mean = ts * (1.0f / Dc);
    const float var = tq * (1.0f / Dc) - mean * mean;
    const float inv = rsqrtf(var + 1e-5f);
    #pragma unroll
    for (int i = 0; i < 3; ++i) {
        const int d = tid + i * 256;
        const float y = (v[i] - mean) * inv * g[d] + be[d];
        outf[(size_t)row * Dc + d] = y;
        outb[(size_t)row * Dc + d] = f32_to_bf16(y);
    }
    __syncthreads();   // red reuse guard
}

// ---------------------------------------------------------------- persistent megakernel
struct MA {
    const unsigned short *bw_ip, *bw_ow, *bw_l1, *bw_l2, *bw_c1;
    const float *ipb, *owb, *g1, *b1, *l1b, *l2b, *g2, *b2;
    float *xA, *xB, *qkvb, *bufS;
    unsigned short *xAb, *xBb, *attnb, *bufHb, *bufCb;
};

__device__ __forceinline__ void gsync(cg::grid_group& g) { __threadfence(); g.sync(); }

__global__ __launch_bounds__(256, 4)
void mega_kernel(MA a) {
    cg::grid_group grid = cg::this_grid();
    __shared__ __align__(16) char smem[32768];   // 32 KB: GEMM dbuf / attn / addln union
    unsigned short* lA = (unsigned short*)smem;          // 2*64*64 shorts
    unsigned short* lB = lA + 2 * 64 * 64;
    const int bid = blockIdx.x;

    for (int l = 0; l < Lc; ++l) {
        // QKV: [1024,768] x [2304,768]^T -> f32 qkvb (bias in-GEMM). 36x16 = 576 tiles.
        if (bid < 576)
            gemm_tile<64, 64, 2, 2, 0>(a.xAb, Dc, a.bw_ip + (size_t)l * 3 * Dc * Dc, Dc,
                                       a.ipb + (size_t)l * 3 * Dc, a.qkvb, 3 * Dc,
                                       TOK, 3 * Dc, Dc, 0, bid % 36, bid / 36, 0, lA, lB);
        gsync(grid);
        // attention: 384 (b,h) jobs
        if (bid < Bc * Hc) attn_stage(a.qkvb, a.attnb, bid, smem);
        gsync(grid);
        // out-proj split-K=4 (K=192): 12x16x4 = 768 jobs -> 4 f32 slabs
        if (bid < 768)
            gemm_tile<64, 64, 2, 2, 0>(a.attnb, Dc, a.bw_ow + (size_t)l * Dc * Dc, Dc,
                                       nullptr, a.bufS, Dc, TOK, Dc, Dc / 4, 0,
                                       bid % 12, (bid / 12) & 15, bid / 192, lA, lB);
        gsync(grid);
        // addLN1: 1024 rows
        addln_stage(a.xA, a.bufS, 4, a.owb + (size_t)l * Dc,
                    a.g1 + (size_t)l * Dc, a.b1 + (size_t)l * Dc, a.xB, a.xBb,
                    bid, (float*)smem);
        gsync(grid);
        // FF1 (relu+bias in-GEMM, bf16 out): 48x16 = 768 jobs, XCD-chunked mapping
        if (bid < 768) {
            const int xcd = bid & 7, p = bid >> 3;
            const int pq = p / 16;
            const int bx = xcd * 6 + pq;        // 48/8 = 6 col-tiles per XCD chunk
            const int by = p - pq * 16;
            gemm_tile<64, 64, 2, 2, 1>(a.xBb, Dc, a.bw_l1 + (size_t)l * DFFc * Dc, Dc,
                                       a.l1b + (size_t)l * DFFc, a.bufHb, DFFc,
                                       TOK, DFFc, Dc, 1, bx, by, 0, lA, lB);
        }
        gsync(grid);
        // FF2 split-K=4 (K=768): 768 jobs -> 4 f32 slabs
        if (bid < 768)
            gemm_tile<64, 64, 2, 2, 0>(a.bufHb, DFFc, a.bw_l2 + (size_t)l * Dc * DFFc, DFFc,
                                       nullptr, a.bufS, Dc, TOK, Dc, DFFc / 4, 0,
                                       bid % 12, (bid / 12) & 15, bid / 192, lA, lB);
        gsync(grid);
        // addLN2: 1024 rows
        addln_stage(a.xB, a.bufS, 4, a.l2b + (size_t)l * Dc,
                    a.g2 + (size_t)l * Dc, a.b2 + (size_t)l * Dc, a.xA, a.xAb,
                    bid, (float*)smem);
        gsync(grid);
    }
    // classifier stage 1: [1024,768] x [128,768]^T -> bf16 bufCb. 2x16 = 32 tiles.
    if (bid < 32)
        gemm_tile<64, 64, 2, 2, 1>(a.xAb, Dc, a.bw_c1, Dc, nullptr, a.bufCb, KC2,
                                   TOK, KC2, Dc, 0, bid % 2, bid / 2, 0, lA, lB);
}

// ---------------------------------------------------------------- standalone wrappers
// (classifier-2 always; layer stages only on cooperative-launch fallback)
template <int BM, int BN, int WM, int WN, int OUTBF>
__global__ __launch_bounds__(256)
void gemm_bf16_kernel(const unsigned short* __restrict__ A, int lda,
                      const unsigned short* __restrict__ B, int ldb,
                      const float* __restrict__ bias, void* __restrict__ Cv,
                      int ldc, int M, int N, int K, int relu, int nxReal) {
    __shared__ __align__(16) unsigned short lA[2 * BM * 64];
    __shared__ __align__(16) unsigned short lB[2 * BN * 64];
    int bx, by;
    if (nxReal > 0) {
        const int gx = gridDim.x, gy = gridDim.y;
        const int lb = blockIdx.y * gx + blockIdx.x;
        const int xcd = lb & 7, p = lb >> 3;
        const int pq = p / gy;
        bx = xcd * (gx >> 3) + pq;
        by = p - pq * gy;
        if (bx >= nxReal) return;
    } else {
        bx = blockIdx.x; by = blockIdx.y;
    }
    gemm_tile<BM, BN, WM, WN, OUTBF>(A, lda, B, ldb, bias, Cv, ldc, M, N, K, relu,
                                     bx, by, blockIdx.z, lA, lB);
}

__global__ __launch_bounds__(256)
void attn_kernel(const float* __restrict__ qkv, unsigned short* __restrict__ outb) {
    __shared__ __align__(16) char smem[32768];
    attn_stage(qkv, outb, blockIdx.x, smem);
}

__global__ __launch_bounds__(256)
void addln_kernel(const float* __restrict__ xa, const float* __restrict__ xs, int nslab,
                  const float* __restrict__ badd, const float* __restrict__ g,
                  const float* __restrict__ be, float* __restrict__ outf,
                  unsigned short* __restrict__ outb) {
    __shared__ float red[8];
    addln_stage(xa, xs, nslab, badd, g, be, outf, outb, blockIdx.x, red);
}

// ---------------------------------------------------------------- launch
extern "C" void kernel_launch(void* const* d_in, const int* in_sizes, int n_in,
                              void* d_out, int out_size, void* d_ws, size_t ws_size,
                              hipStream_t stream) {
    const float* lhs   = (const float*)d_in[0];
    const float* attnw = (const float*)d_in[1];
    // d_in[2] attn_b: scalar, cancels in softmax
    const float* ipw = (const float*)d_in[3];
    const float* ipb = (const float*)d_in[4];
    const float* oww = (const float*)d_in[5];
    const float* owb = (const float*)d_in[6];
    const float* g1  = (const float*)d_in[7];
    const float* b1  = (const float*)d_in[8];
    const float* l1w = (const float*)d_in[9];
    const float* l1b = (const float*)d_in[10];
    const float* l2w = (const float*)d_in[11];
    const float* l2b = (const float*)d_in[12];
    const float* g2  = (const float*)d_in[13];
    const float* b2  = (const float*)d_in[14];
    const float* cw1 = (const float*)d_in[15];
    const float* cw2 = (const float*)d_in[16];
    const float* cb2 = (const float*)d_in[17];
    const int* pos   = (const int*)d_in[18];
    const int* emask = (const int*)d_in[19];
    float* out = (float*)d_out;

    constexpr size_t N_IP = (size_t)Lc * 3 * Dc * Dc;   // 7,077,888
    constexpr size_t N_OW = (size_t)Lc * Dc * Dc;       // 2,359,296
    constexpr size_t N_L1 = (size_t)Lc * DFFc * Dc;     // 9,437,184
    constexpr size_t N_L2 = (size_t)Lc * Dc * DFFc;     // 9,437,184
    constexpr size_t N_C1 = (size_t)KC2 * Dc;           // 98,304 (128 rows, 28 zero)

    // ---- memory map ----
    // d_ws: bw_c2 [E,128] bf16 (25.6 MB) + bufCb [1024,128] bf16 (0.26 MB).
    //       (final-GEMM B staging may over-read <100 KB past bw_c2 -> lands in bufCb, safe)
    // d_out TAIL (~96 MB of 409.6 MB; dead before final GEMM overwrites all of d_out):
    //       f32 activations, then bf16 weights + bf16 activations.
    char* ws = (char*)d_ws;
    unsigned short* bw_c2 = (unsigned short*)ws;                 // [E,128] bf16
    unsigned short* bufCb = bw_c2 + (size_t)Ec * KC2;            // [1024,128] bf16

    constexpr size_t F_XA   = (size_t)TOK * Dc;          // 786,432
    constexpr size_t F_QKV  = (size_t)TOK * 3 * Dc;      // 2,359,296
    constexpr size_t F_SLAB = (size_t)4 * TOK * Dc;      // 3,145,728
    constexpr size_t S_ACT  = (size_t)TOK * Dc;          // bf16 activation count
    constexpr size_t S_FFH  = (size_t)TOK * DFFc;
    constexpr size_t tail_bytes =
        4 * (F_XA + F_XA + F_QKV + F_SLAB) +
        2 * (N_IP + N_OW + N_L1 + N_L2 + N_C1 + 3 * S_ACT + S_FFH);

    const size_t out_bytes = (size_t)out_size * 4;
    char* tail = (char*)d_out + ((out_bytes - tail_bytes) & ~(size_t)255);

    float* xA   = (float*)tail;
    float* xB   = xA + F_XA;
    float* qkvb = xB + F_XA;                                     // [1024,2304] f32
    float* bufS = qkvb + F_QKV;                                  // 4 split-K slabs [1024,768] f32
    unsigned short* bw_ip = (unsigned short*)(bufS + F_SLAB);
    unsigned short* bw_ow = bw_ip + N_IP;
    unsigned short* bw_l1 = bw_ow + N_OW;
    unsigned short* bw_l2 = bw_l1 + N_L1;
    unsigned short* bw_c1 = bw_l2 + N_L2;
    unsigned short* xAb   = bw_c1 + N_C1;
    unsigned short* xBb   = xAb + S_ACT;
    unsigned short* attnb = xBb + S_ACT;                         // attn out bf16
    unsigned short* bufHb = attnb + S_ACT;                       // FF hidden bf16 [1024,3072]

    // fused front: weight cvt (6 segments incl. cls_w1 zero-pad rows) + cls_w2 cvt + pool
    {
        CvtSegs segs{};
        const float* srcs[6] = {ipw, oww, l1w, l2w, cw1, nullptr};
        unsigned short* dsts[6] = {bw_ip, bw_ow, bw_l1, bw_l2, bw_c1, bw_c1 + (size_t)100 * Dc};
        const unsigned int cnt[6] = {(unsigned)(N_IP / 4), (unsigned)(N_OW / 4),
                                     (unsigned)(N_L1 / 4), (unsigned)(N_L2 / 4),
                                     (unsigned)(100 * Dc / 4), (unsigned)(28 * Dc / 4)};
        unsigned int acc = 0;
        for (int i = 0; i < 6; ++i) { segs.src[i] = srcs[i]; segs.dst[i] = dsts[i]; acc += cnt[i]; segs.end[i] = acc; }
        segs.src[6] = nullptr; segs.dst[6] = dsts[5]; segs.end[6] = 0xFFFFFFFFu;
        segs.total = acc;
        front_kernel<<<FB_CVT1 + FB_CVT2 + FB_POOL, 256, 0, stream>>>(
            segs, cw2, bw_c2, lhs, attnw, pos, emask, xA, xAb);
    }

    // persistent cooperative megakernel: 4 layers + classifier-1 (29 grid syncs)
    MA ma{bw_ip, bw_ow, bw_l1, bw_l2, bw_c1,
          ipb, owb, g1, b1, l1b, l2b, g2, b2,
          xA, xB, qkvb, bufS,
          xAb, xBb, attnb, bufHb, bufCb};
    void* kargs[] = {&ma};
    hipError_t ce = hipLaunchCooperativeKernel((const void*)mega_kernel,
                                               dim3(1024), dim3(256), kargs, 0, stream);
    if (ce != hipSuccess) {
        // fallback: R4-style per-stage dispatch sequence (same device code)
        auto g64 = [&](const unsigned short* A, int lda, const unsigned short* B, int ldb,
                       const float* bias, void* C, int ldc, int N, int K, int relu,
                       int ks, int outbf, bool swz) {
            int gx = (N + 63) / 64, nx = -1;
            if (swz) { nx = gx; gx = (gx + 7) & ~7; }
            dim3 grid(gx, TOK / 64, ks);
            if (outbf) gemm_bf16_kernel<64, 64, 2, 2, 1><<<grid, 256, 0, stream>>>(A, lda, B, ldb, bias, C, ldc, TOK, N, K, relu, nx);
            else       gemm_bf16_kernel<64, 64, 2, 2, 0><<<grid, 256, 0, stream>>>(A, lda, B, ldb, bias, C, ldc, TOK, N, K, relu, nx);
        };
        for (int l = 0; l < Lc; ++l) {
            g64(xAb, Dc, bw_ip + (size_t)l * 3 * Dc * Dc, Dc, ipb + (size_t)l * 3 * Dc,
                qkvb, 3 * Dc, 3 * Dc, Dc, 0, 1, 0, false);
            attn_kernel<<<Bc * Hc, 256, 0, stream>>>(qkvb, attnb);
            g64(attnb, Dc, bw_ow + (size_t)l * Dc * Dc, Dc, nullptr,
                bufS, Dc, Dc, Dc / 4, 0, 4, 0, false);
            addln_kernel<<<TOK, 256, 0, stream>>>(xA, bufS, 4, owb + (size_t)l * Dc,
                                                  g1 + (size_t)l * Dc, b1 + (size_t)l * Dc, xB, xBb);
            g64(xBb, Dc, bw_l1 + (size_t)l * DFFc * Dc, Dc, l1b + (size_t)l * DFFc,
                bufHb, DFFc, DFFc, Dc, 1, 1, 1, true);
            g64(bufHb, DFFc, bw_l2 + (size_t)l * Dc * DFFc, DFFc, nullptr,
                bufS, Dc, Dc, DFFc / 4, 0, 4, 0, false);
            addln_kernel<<<TOK, 256, 0, stream>>>(xB, bufS, 4, l2b + (size_t)l * Dc,
                                                  g2 + (size_t)l * Dc, b2 + (size_t)l * Dc, xA, xAb);
        }
        g64(xAb, Dc, bw_c1, Dc, nullptr, bufCb, KC2, KC2, Dc, 0, 1, 1, false);
    }

    // classifier stage 2: [1024,128] x [100000,128]^T -> f32 out; XCD chunk swizzle
    {
        int nx = (Ec + 127) / 128;          // 782 real col tiles
        int gx = (nx + 7) & ~7;             // 784 padded
        dim3 grid(gx, TOK / 128, 1);
        gemm_bf16_kernel<128, 128, 4, 4, 0><<<grid, 256, 0, stream>>>(
            bufCb, KC2, bw_c2, KC2, cb2, out, Ec, TOK, Ec, KC2, 0, nx);
    }
}

// Round 6
// 981.820 us; speedup vs baseline: 7.1332x; 7.1332x over previous
//
#include <hip/hip_runtime.h>

// Problem constants
constexpr int Bc = 32, Sc = 512, Dc = 768, Mc = 32, Tc = 30;
constexpr int Hc = 12, DFFc = 3072, Lc = 4, Ec = 100000, HDc = 64;
constexpr int TOK = Bc * Mc; // 1024 token rows
constexpr int KC2 = 128;     // padded K for classifier GEMMs (multiple of BK=64)

typedef float floatx4 __attribute__((ext_vector_type(4)));
typedef __bf16 bfrag8 __attribute__((ext_vector_type(8)));
typedef unsigned short usx8 __attribute__((ext_vector_type(8)));
typedef unsigned short usx4 __attribute__((ext_vector_type(4)));

__device__ __forceinline__ unsigned short f32_to_bf16(float f) {
    unsigned int u = __float_as_uint(f);
    unsigned int r = (u + 0x7FFFu + ((u >> 16) & 1u)) >> 16; // RNE
    return (unsigned short)r;
}

// async global->LDS, 16B per lane; lds ptr must be wave-uniform, gsrc is per-lane
__device__ __forceinline__ void gload_lds16(const void* gsrc, void* lds) {
    __builtin_amdgcn_global_load_lds((const unsigned int*)gsrc, (unsigned int*)lds, 16, 0, 0);
}

// ---------------------------------------------------------------- fused front kernel
// block ranges: [0,1536) weight cvt segs; [1536,2048) cls_w2 cvt; [2048,3072) mention pool
struct CvtSegs {
    const float* src[7];
    unsigned short* dst[7];
    unsigned int end[7];   // cumulative counts in float4-chunks
    unsigned int total;
};

constexpr int FB_CVT1 = 1536, FB_CVT2 = 512, FB_POOL = TOK;

__global__ __launch_bounds__(256)
void front_kernel(CvtSegs a, const float* __restrict__ cw2, unsigned short* __restrict__ bw_c2,
                  const float* __restrict__ lhs, const float* __restrict__ attn_w,
                  const int* __restrict__ pos, const int* __restrict__ emask,
                  float* __restrict__ x0, unsigned short* __restrict__ x0b) {
    const int bid = blockIdx.x;
    const int tid = threadIdx.x;

    if (bid < FB_CVT1) {
        const unsigned int stride = FB_CVT1 * 256;
        for (unsigned int i = bid * 256 + tid; i < a.total; i += stride) {
            int s = 0;
            while (i >= a.end[s]) ++s;
            const unsigned int off = i - (s ? a.end[s - 1] : 0u);
            usx4 o = (usx4)0;
            if (a.src[s]) {
                floatx4 v = *(const floatx4*)(a.src[s] + 4 * (size_t)off);
                #pragma unroll
                for (int j = 0; j < 4; ++j) o[j] = f32_to_bf16(v[j]);
            }
            *(usx4*)(a.dst[s] + 4 * (size_t)off) = o;
        }
        return;
    }
    if (bid < FB_CVT1 + FB_CVT2) {
        const int total = Ec * (KC2 / 8);
        const int stride = FB_CVT2 * 256;
        for (int c = (bid - FB_CVT1) * 256 + tid; c < total; c += stride) {
            const int row = c >> 4, j = c & 15;
            const int col0 = j * 8;
            const float* sp = cw2 + (size_t)row * 100 + col0;
            usx8 o = (usx8)0;
            if (col0 + 8 <= 100) {
                floatx4 v0 = *(const floatx4*)(sp);
                floatx4 v1 = *(const floatx4*)(sp + 4);
                #pragma unroll
                for (int jj = 0; jj < 4; ++jj) { o[jj] = f32_to_bf16(v0[jj]); o[4 + jj] = f32_to_bf16(v1[jj]); }
            } else if (col0 < 100) {
                #pragma unroll
                for (int jj = 0; jj < 8; ++jj)
                    if (col0 + jj < 100) o[jj] = f32_to_bf16(sp[jj]);
            }
            *(usx8*)(bw_c2 + (size_t)row * KC2 + col0) = o;
        }
        return;
    }

    // ---- mention pool ----
    const int bm = bid - (FB_CVT1 + FB_CVT2);   // b*32+m
    const int b = bm >> 5;
    __shared__ float s_logit[32];
    __shared__ float s_w[32];
    __shared__ int s_valid[32];

    if (tid == 0) {
        int em = emask[bm];
        int ok = 1;
        for (int t = 0; t < Tc; ++t) {
            if (pos[bm * Tc + t] == -1) ok = 0;
            s_valid[t] = (ok && em) ? 1 : 0;
        }
    }
    __syncthreads();

    const int wid = tid >> 6, lane = tid & 63;
    for (int t = wid; t < Tc; t += 4) {
        float p = 0.f;
        const float* row = lhs + ((size_t)b * Sc + t) * Dc;
        for (int d = lane; d < Dc; d += 64) p += row[d] * attn_w[d];
        #pragma unroll
        for (int off = 32; off > 0; off >>= 1) p += __shfl_down(p, off);
        if (lane == 0) s_logit[t] = s_valid[t] ? p : 0.0f;  // attn_b cancels in softmax
    }
    __syncthreads();
    if (tid == 0) {
        float mx = -1e30f;
        for (int t = 0; t < Tc; ++t) mx = fmaxf(mx, s_logit[t]);
        float sum = 0.f;
        for (int t = 0; t < Tc; ++t) { float e = expf(s_logit[t] - mx); s_w[t] = e; sum += e; }
        float inv = 1.0f / sum;
        for (int t = 0; t < Tc; ++t) s_w[t] = s_valid[t] ? s_w[t] * inv : 0.0f;
    }
    __syncthreads();
    for (int d = tid; d < Dc; d += 256) {
        float acc = 0.f;
        for (int t = 0; t < Tc; ++t) acc += s_w[t] * lhs[((size_t)b * Sc + t) * Dc + d];
        x0[(size_t)bm * Dc + d] = acc;
        x0b[(size_t)bm * Dc + d] = f32_to_bf16(acc);
    }
}

// ---------------------------------------------------------------- GEMM  C = A @ B^T (+bias) (opt relu)
// A: bf16 [M,lda]; B: bf16 [N,ldb]; C: f32 or bf16 [M,ldc].
// REQUIRES: M % BM == 0, K % 64 == 0, 16B-aligned rows. Stores guarded by col<N;
// B OOB rows must land in readable memory (see memory-map note at call site).
// Staging: global_load_lds width-16, linear LDS dest + pre-swizzled global source
// (cb ^ ((row&7)<<4)); ds_read applies the same XOR (T2, rule #21).
// SINGLE-buffered (R3-proven): dbuf doubled LDS and cut cls2 occupancy 3->2 blocks/CU.
// NO min-waves launch_bounds: R5 showed forcing occupancy spills the GEMM (VGPR=64).
// Split-K via blockIdx.z: A,B advance z*K cols; C advances z*M*ldc (partial slabs).
// nxReal>0 enables XCD chunk swizzle (requires gridDim.x % 8 == 0); padded col-tiles exit.
template <int BM, int BN, int WM, int WN, int OUTBF>
__global__ __launch_bounds__(256)
void gemm_bf16_kernel(const unsigned short* __restrict__ A, int lda,
                      const unsigned short* __restrict__ B, int ldb,
                      const float* __restrict__ bias, void* __restrict__ Cv,
                      int ldc, int M, int N, int K, int relu, int nxReal) {
    constexpr int BK = 64;
    __shared__ unsigned short lA[BM * BK];
    __shared__ unsigned short lB[BN * BK];

    int bx, by;
    if (nxReal > 0) {
        const int gx = gridDim.x, gy = gridDim.y;
        const int lb = blockIdx.y * gx + blockIdx.x;
        const int xcd = lb & 7, p = lb >> 3;
        const int pq = p / gy;
        bx = xcd * (gx >> 3) + pq;
        by = p - pq * gy;
        if (bx >= nxReal) return;   // uniform across block, before any barrier
    } else {
        bx = blockIdx.x; by = blockIdx.y;
    }
    const int z = blockIdx.z;
    A += (size_t)z * K;
    B += (size_t)z * K;

    const int tid = threadIdx.x;
    const int bm0 = by * BM;
    const int bn0 = bx * BN;

    const int wid = tid >> 6;
    const int lane = tid & 63;
    const int quad = lane >> 4;
    const int l16 = lane & 15;
    const int wr = (wid >> 1) * (WM * 16);
    const int wc = (wid & 1) * (WN * 16);

    floatx4 acc[WM][WN] = {};

    for (int k0 = 0; k0 < K; k0 += BK) {
        // stage A: BM rows x 128 B, 1024-B wave chunks; source byte pre-swizzled
        #pragma unroll
        for (int it = 0; it < BM / 32; ++it) {
            const int chunk = wid * (BM / 32) + it;       // wave-uniform
            const int boff = chunk * 1024 + lane * 16;
            const int row = boff >> 7;
            const int cb = (boff & 127) ^ ((row & 7) << 4);
            gload_lds16((const char*)(A + (size_t)(bm0 + row) * lda + k0) + cb,
                        &lA[chunk * 512]);
        }
        // stage B
        #pragma unroll
        for (int it = 0; it < BN / 32; ++it) {
            const int chunk = wid * (BN / 32) + it;
            const int boff = chunk * 1024 + lane * 16;
            const int row = boff >> 7;
            const int cb = (boff & 127) ^ ((row & 7) << 4);
            gload_lds16((const char*)(B + (size_t)(bn0 + row) * ldb + k0) + cb,
                        &lB[chunk * 512]);
        }
        __syncthreads();   // drains vmcnt (gload_lds) + lgkmcnt
        #pragma unroll
        for (int kk = 0; kk < BK; kk += 32) {
            bfrag8 af[WM], bfr[WN];
            #pragma unroll
            for (int i = 0; i < WM; ++i) {
                const int rowA = wr + i * 16 + l16;
                af[i] = *(const bfrag8*)((const char*)lA + rowA * 128 +
                                         ((kk * 2 + quad * 16) ^ ((rowA & 7) << 4)));
            }
            #pragma unroll
            for (int j = 0; j < WN; ++j) {
                const int rowB = wc + j * 16 + l16;
                bfr[j] = *(const bfrag8*)((const char*)lB + rowB * 128 +
                                          ((kk * 2 + quad * 16) ^ ((rowB & 7) << 4)));
            }
            #pragma unroll
            for (int i = 0; i < WM; ++i)
                #pragma unroll
                for (int j = 0; j < WN; ++j)
                    acc[i][j] = __builtin_amdgcn_mfma_f32_16x16x32_bf16(af[i], bfr[j], acc[i][j], 0, 0, 0);
        }
        __syncthreads();
    }

    #pragma unroll
    for (int i = 0; i < WM; ++i) {
        #pragma unroll
        for (int j = 0; j < WN; ++j) {
            const int col = bn0 + wc + j * 16 + l16;
            if (col < N) {
                const int row0 = bm0 + wr + i * 16 + quad * 4;
                const float bv = bias ? bias[col] : 0.0f;
                #pragma unroll
                for (int r = 0; r < 4; ++r) {
                    float v = acc[i][j][r] + bv;
                    if (relu) v = fmaxf(v, 0.0f);
                    const size_t idx = (size_t)z * M * ldc + (size_t)(row0 + r) * ldc + col;
                    if (OUTBF) ((unsigned short*)Cv)[idx] = f32_to_bf16(v);
                    else       ((float*)Cv)[idx] = v;
                }
            }
        }
    }
}

// ---------------------------------------------------------------- fused QKV + attention
// One block per (b,h). GEMM: A = xAb rows [32b,32b+32) [32,768] bf16; B = three 64-row
// slices of this layer's in_proj weight (Q: h*64.., K: 768+h*64.., V: 1536+h*64..),
// i.e. a [192,768] bf16 operand. Same staging/swizzle/MFMA K-order as gemm_bf16_kernel
// => accumulators bit-identical to the unfused QKV GEMM. Epilogue writes QKV+bias to
// LDS f32 (replacing the old qkvb global round-trip), then runs the verbatim attention
// arithmetic and emits bf16 attn output.
__global__ __launch_bounds__(256)
void fqa_kernel(const unsigned short* __restrict__ xAb,
                const unsigned short* __restrict__ bw_ip_l,
                const float* __restrict__ ipb_l,
                unsigned short* __restrict__ attnb) {
    __shared__ __align__(16) char smem[29696];
    unsigned short* sA = (unsigned short*)smem;            // [32][64] bf16 = 4 KB
    unsigned short* sB = (unsigned short*)(smem + 4096);   // [192][64] bf16 = 24 KB
    float* qkvf = (float*)smem;                            // [3*32][66] f32 = 25,344 B (reuses staging)
    float (*sS)[33] = (float(*)[33])(smem + 25344);        // [32][33] f32 = 4,224 B

    const int bh = blockIdx.x;
    const int b32 = (bh / Hc) * 32;
    const int h = bh % Hc;
    const int tid = threadIdx.x;
    const int wid = tid >> 6, lane = tid & 63;
    const int quad = lane >> 4, l16 = lane & 15;

    floatx4 acc[2][3] = {};

    for (int k0 = 0; k0 < Dc; k0 += 64) {
        // 28 x 1024-B chunks (A:4, B:24), 7 per wave
        #pragma unroll
        for (int it = 0; it < 7; ++it) {
            const int c = wid * 7 + it;                   // wave-uniform
            if (c < 4) {
                const int boff = c * 1024 + lane * 16;
                const int row = boff >> 7;                // 0..31
                const int cb = (boff & 127) ^ ((row & 7) << 4);
                gload_lds16((const char*)(xAb + (size_t)(b32 + row) * Dc + k0) + cb,
                            &sA[c * 512]);
            } else {
                const int boff = (c - 4) * 1024 + lane * 16;
                const int row = boff >> 7;                // 0..191
                const int cb = (boff & 127) ^ ((row & 7) << 4);
                const int grow = (row >> 6) * Dc + h * 64 + (row & 63); // Q/K/V slice row
                gload_lds16((const char*)(bw_ip_l + (size_t)grow * Dc + k0) + cb,
                            &sB[(c - 4) * 512]);
            }
        }
        __syncthreads();
        #pragma unroll
        for (int kk = 0; kk < 64; kk += 32) {
            bfrag8 af[2], bfr[3];
            #pragma unroll
            for (int i = 0; i < 2; ++i) {
                const int rowA = i * 16 + l16;
                af[i] = *(const bfrag8*)((const char*)sA + rowA * 128 +
                                         ((kk * 2 + quad * 16) ^ ((rowA & 7) << 4)));
            }
            #pragma unroll
            for (int j = 0; j < 3; ++j) {
                const int rowB = (wid * 3 + j) * 16 + l16;
                bfr[j] = *(const bfrag8*)((const char*)sB + rowB * 128 +
                                          ((kk * 2 + quad * 16) ^ ((rowB & 7) << 4)));
            }
            #pragma unroll
            for (int i = 0; i < 2; ++i)
                #pragma unroll
                for (int j = 0; j < 3; ++j)
                    acc[i][j] = __builtin_amdgcn_mfma_f32_16x16x32_bf16(af[i], bfr[j], acc[i][j], 0, 0, 0);
        }
        __syncthreads();   // all ds_reads done -> staging region may be reused below
    }

    // epilogue: QKV + bias -> LDS f32 (Q rows 0..31, K rows 32..63, V rows 64..95)
    #pragma unroll
    for (int i = 0; i < 2; ++i) {
        #pragma unroll
        for (int j = 0; j < 3; ++j) {
            const int col = (wid * 3 + j) * 16 + l16;     // 0..191
            const int p = col >> 6, pc = col & 63;
            const float bv = ipb_l[p * Dc + h * 64 + pc];
            const int row0 = i * 16 + quad * 4;
            #pragma unroll
            for (int r = 0; r < 4; ++r)
                qkvf[(p * 32 + row0 + r) * 66 + pc] = acc[i][j][r] + bv;
        }
    }
    __syncthreads();

    // ---- attention (verbatim arithmetic of the old attn kernel, LDS-sourced) ----
    const int m = tid >> 3;
    const int c0 = (tid & 7) * 8;
    #pragma unroll
    for (int u = 0; u < 4; ++u) {
        const int e = tid * 4 + u;
        const int q = e >> 5, k = e & 31;
        float s = 0.f;
        #pragma unroll
        for (int d = 0; d < HDc; ++d)
            s += qkvf[q * 66 + d] * qkvf[(32 + k) * 66 + d];
        sS[q][k] = s * 0.125f;
    }
    __syncthreads();
    if (tid < 32) {
        float mx = -1e30f;
        for (int k = 0; k < 32; ++k) mx = fmaxf(mx, sS[tid][k]);
        float sum = 0.f;
        for (int k = 0; k < 32; ++k) { float e = expf(sS[tid][k] - mx); sS[tid][k] = e; sum += e; }
        const float inv = 1.0f / sum;
        for (int k = 0; k < 32; ++k) sS[tid][k] *= inv;
    }
    __syncthreads();
    float o[8] = {};
    for (int k = 0; k < 32; ++k) {
        const float p = sS[m][k];
        #pragma unroll
        for (int j = 0; j < 8; ++j) o[j] += p * qkvf[(64 + k) * 66 + c0 + j];
    }
    usx8 o8;
    #pragma unroll
    for (int j = 0; j < 8; ++j) o8[j] = f32_to_bf16(o[j]);
    *(usx8*)(&attnb[((size_t)(b32 + m)) * Dc + h * HDc + c0]) = o8;
}

// ---------------------------------------------------------------- residual + split-K sum + bias + layernorm
// out = LN(xa + sum_{s<nslab} xs[s] + badd) ; writes f32 and bf16 copies
__global__ __launch_bounds__(256)
void addln_kernel(const float* __restrict__ xa, const float* __restrict__ xs, int nslab,
                  const float* __restrict__ badd, const float* __restrict__ g,
                  const float* __restrict__ be, float* __restrict__ outf,
                  unsigned short* __restrict__ outb) {
    const int row = blockIdx.x;
    const int tid = threadIdx.x;
    __shared__ float red[8];
    float v[3];
    float s = 0.f, sq = 0.f;
    #pragma unroll
    for (int i = 0; i < 3; ++i) {
        const int d = tid + i * 256;
        float x = xa[(size_t)row * Dc + d] + badd[d];
        for (int sl = 0; sl < nslab; ++sl)
            x += xs[((size_t)sl * TOK + row) * Dc + d];
        v[i] = x; s += x; sq += x * x;
    }
    #pragma unroll
    for (int off = 32; off > 0; off >>= 1) {
        s += __shfl_down(s, off);
        sq += __shfl_down(sq, off);
    }
    if ((tid & 63) == 0) { red[tid >> 6] = s; red[4 + (tid >> 6)] = sq; }
    __syncthreads();
    const float ts = red[0] + red[1] + red[2] + red[3];
    const float tq = red[4] + red[5] + red[6] + red[7];
    const float mean = ts * (1.0f / Dc);
    const float var = tq * (1.0f / Dc) - mean * mean;
    const float inv = rsqrtf(var + 1e-5f);
    #pragma unroll
    for (int i = 0; i < 3; ++i) {
        const int d = tid + i * 256;
        const float y = (v[i] - mean) * inv * g[d] + be[d];
        outf[(size_t)row * Dc + d] = y;
        outb[(size_t)row * Dc + d] = f32_to_bf16(y);
    }
}

// ---------------------------------------------------------------- launch
extern "C" void kernel_launch(void* const* d_in, const int* in_sizes, int n_in,
                              void* d_out, int out_size, void* d_ws, size_t ws_size,
                              hipStream_t stream) {
    const float* lhs   = (const float*)d_in[0];
    const float* attnw = (const float*)d_in[1];
    // d_in[2] attn_b: scalar, cancels in softmax
    const float* ipw = (const float*)d_in[3];
    const float* ipb = (const float*)d_in[4];
    const float* oww = (const float*)d_in[5];
    const float* owb = (const float*)d_in[6];
    const float* g1  = (const float*)d_in[7];
    const float* b1  = (const float*)d_in[8];
    const float* l1w = (const float*)d_in[9];
    const float* l1b = (const float*)d_in[10];
    const float* l2w = (const float*)d_in[11];
    const float* l2b = (const float*)d_in[12];
    const float* g2  = (const float*)d_in[13];
    const float* b2  = (const float*)d_in[14];
    const float* cw1 = (const float*)d_in[15];
    const float* cw2 = (const float*)d_in[16];
    const float* cb2 = (const float*)d_in[17];
    const int* pos   = (const int*)d_in[18];
    const int* emask = (const int*)d_in[19];
    float* out = (float*)d_out;

    constexpr size_t N_IP = (size_t)Lc * 3 * Dc * Dc;   // 7,077,888
    constexpr size_t N_OW = (size_t)Lc * Dc * Dc;       // 2,359,296
    constexpr size_t N_L1 = (size_t)Lc * DFFc * Dc;     // 9,437,184
    constexpr size_t N_L2 = (size_t)Lc * Dc * DFFc;     // 9,437,184
    constexpr size_t N_C1 = (size_t)KC2 * Dc;           // 98,304 (128 rows, 28 zero)

    // ---- memory map ----
    // d_ws: bw_c2 [E,128] bf16 (25.6 MB) + bufCb [1024,128] bf16 (0.26 MB).
    //       (final-GEMM B staging may over-read <100 KB past bw_c2 -> lands in bufCb, safe)
    // d_out TAIL (~96 MB of 409.6 MB; dead before final GEMM overwrites all of d_out):
    //       f32 activations, then bf16 weights + bf16 activations.
    char* ws = (char*)d_ws;
    unsigned short* bw_c2 = (unsigned short*)ws;                 // [E,128] bf16
    unsigned short* bufCb = bw_c2 + (size_t)Ec * KC2;            // [1024,128] bf16

    constexpr size_t F_XA   = (size_t)TOK * Dc;          // 786,432
    constexpr size_t F_QKV  = (size_t)TOK * 3 * Dc;      // retained (unused) to keep map stable
    constexpr size_t F_SLAB = (size_t)4 * TOK * Dc;      // 3,145,728
    constexpr size_t S_ACT  = (size_t)TOK * Dc;          // bf16 activation count
    constexpr size_t S_FFH  = (size_t)TOK * DFFc;
    constexpr size_t tail_bytes =
        4 * (F_XA + F_XA + F_QKV + F_SLAB) +
        2 * (N_IP + N_OW + N_L1 + N_L2 + N_C1 + 3 * S_ACT + S_FFH);

    const size_t out_bytes = (size_t)out_size * 4;
    char* tail = (char*)d_out + ((out_bytes - tail_bytes) & ~(size_t)255);

    float* xA   = (float*)tail;
    float* xB   = xA + F_XA;
    float* qkvb = xB + F_XA;                                     // unused (fqa keeps QKV in LDS)
    float* bufS = qkvb + F_QKV;                                  // 4 split-K slabs [1024,768] f32
    unsigned short* bw_ip = (unsigned short*)(bufS + F_SLAB);
    unsigned short* bw_ow = bw_ip + N_IP;
    unsigned short* bw_l1 = bw_ow + N_OW;
    unsigned short* bw_l2 = bw_l1 + N_L1;
    unsigned short* bw_c1 = bw_l2 + N_L2;
    unsigned short* xAb   = bw_c1 + N_C1;
    unsigned short* xBb   = xAb + S_ACT;
    unsigned short* attnb = xBb + S_ACT;                         // attn out bf16
    unsigned short* bufHb = attnb + S_ACT;                       // FF hidden bf16 [1024,3072]

    // fused front: weight cvt (6 segments incl. cls_w1 zero-pad rows) + cls_w2 cvt + pool
    {
        CvtSegs segs{};
        const float* srcs[6] = {ipw, oww, l1w, l2w, cw1, nullptr};
        unsigned short* dsts[6] = {bw_ip, bw_ow, bw_l1, bw_l2, bw_c1, bw_c1 + (size_t)100 * Dc};
        const unsigned int cnt[6] = {(unsigned)(N_IP / 4), (unsigned)(N_OW / 4),
                                     (unsigned)(N_L1 / 4), (unsigned)(N_L2 / 4),
                                     (unsigned)(100 * Dc / 4), (unsigned)(28 * Dc / 4)};
        unsigned int acc = 0;
        for (int i = 0; i < 6; ++i) { segs.src[i] = srcs[i]; segs.dst[i] = dsts[i]; acc += cnt[i]; segs.end[i] = acc; }
        segs.src[6] = nullptr; segs.dst[6] = dsts[5]; segs.end[6] = 0xFFFFFFFFu;
        segs.total = acc;
        front_kernel<<<FB_CVT1 + FB_CVT2 + FB_POOL, 256, 0, stream>>>(
            segs, cw2, bw_c2, lhs, attnw, pos, emask, xA, xAb);
    }

    auto g64 = [&](const unsigned short* A, int lda, const unsigned short* B, int ldb,
                   const float* bias, void* C, int ldc, int N, int K, int relu,
                   int ks, int outbf, bool swz) {
        int gx = (N + 63) / 64, nx = -1;
        if (swz) { nx = gx; gx = (gx + 7) & ~7; }
        dim3 grid(gx, TOK / 64, ks);
        if (outbf) gemm_bf16_kernel<64, 64, 2, 2, 1><<<grid, 256, 0, stream>>>(A, lda, B, ldb, bias, C, ldc, TOK, N, K, relu, nx);
        else       gemm_bf16_kernel<64, 64, 2, 2, 0><<<grid, 256, 0, stream>>>(A, lda, B, ldb, bias, C, ldc, TOK, N, K, relu, nx);
    };

    for (int l = 0; l < Lc; ++l) {
        // fused QKV+attention: 384 (b,h) blocks -> attnb (bf16)
        fqa_kernel<<<Bc * Hc, 256, 0, stream>>>(
            xAb, bw_ip + (size_t)l * 3 * Dc * Dc, ipb + (size_t)l * 3 * Dc, attnb);
        // out-proj: split-K=4 (K=192 each) -> 4 f32 slabs; bias folded into addln
        g64(attnb, Dc, bw_ow + (size_t)l * Dc * Dc, Dc, nullptr,
            bufS, Dc, Dc, Dc / 4, 0, 4, 0, false);
        addln_kernel<<<TOK, 256, 0, stream>>>(xA, bufS, 4, owb + (size_t)l * Dc,
                                              g1 + (size_t)l * Dc, b1 + (size_t)l * Dc, xB, xBb);
        // FF1: relu + bias in-GEMM, bf16 out (only feeds FF2); XCD swizzle (gx=48 exact)
        g64(xBb, Dc, bw_l1 + (size_t)l * DFFc * Dc, Dc, l1b + (size_t)l * DFFc,
            bufHb, DFFc, DFFc, Dc, 1, 1, 1, true);
        // FF2: split-K=4 (K=768 each) -> 4 f32 slabs; bias folded into addln
        g64(bufHb, DFFc, bw_l2 + (size_t)l * Dc * DFFc, DFFc, nullptr,
            bufS, Dc, Dc, DFFc / 4, 0, 4, 0, false);
        addln_kernel<<<TOK, 256, 0, stream>>>(xB, bufS, 4, l2b + (size_t)l * Dc,
                                              g2 + (size_t)l * Dc, b2 + (size_t)l * Dc, xA, xAb);
    }

    // classifier stage 1: N=128 (28 zero rows in bw_c1 -> zero pad cols), bf16 out
    g64(xAb, Dc, bw_c1, Dc, nullptr, bufCb, KC2, KC2, Dc, 0, 1, 1, false);
    // classifier stage 2: [1024,128] x [100000,128]^T -> f32 out; XCD chunk swizzle
    {
        int nx = (Ec + 127) / 128;          // 782 real col tiles
        int gx = (nx + 7) & ~7;             // 784 padded
        dim3 grid(gx, TOK / 128, 1);
        gemm_bf16_kernel<128, 128, 4, 4, 0><<<grid, 256, 0, stream>>>(
            bufCb, KC2, bw_c2, KC2, cb2, out, Ec, TOK, Ec, KC2, 0, nx);
    }
}